// Round 1
// baseline (87.204 us; speedup 1.0000x reference)
//
#include <hip/hip_runtime.h>

// BlurredPhonemeEmbedding on MI355X.
// B=32, T=8192, V=2820, D=64. Output (B,T,D) f32 = 64 MB -> write-bound.
// One fused kernel: per 256-position tile, stage ids (+768 halo) in LDS,
// build segment-boundary bitmask via __ballot, derive per-position blend
// weight + neighbor id with word-wise bit scans, then float4 gather-blend.

#define BFC   0.3f
#define TILE  256
#define HALO  768
#define SSTAGE (TILE + 2 * HALO)   // 1792 staged positions
#define NWORD  (SSTAGE / 64)       // 28 bitmask words
#define NTH    256

// Rare fallback paths (halo exhausted): scan global ids directly (L2-hot).
__device__ __forceinline__ int seg_start_global(const int* __restrict__ row, int t) {
    while (t > 0 && row[t] == row[t - 1]) --t;   // stop at is_start
    return t;
}
__device__ __forceinline__ int seg_end_global(const int* __restrict__ row, int t, int T) {
    ++t;
    while (t < T && row[t] == row[t - 1]) ++t;   // smallest boundary > t (T counts)
    return t;
}

// largest set bit index <= li, or -1
__device__ __forceinline__ int bits_le(const unsigned long long* bm, int li) {
    int wi = li >> 6, bi = li & 63;
    unsigned long long m = bm[wi] & (~0ULL >> (63 - bi));
    while (m == 0ULL && wi > 0) m = bm[--wi];
    return m ? ((wi << 6) + 63 - __clzll((long long)m)) : -1;
}
// smallest set bit index > li, or -1
__device__ __forceinline__ int bits_gt(const unsigned long long* bm, int li) {
    int wi = li >> 6, bi = li & 63;
    unsigned long long m = (bi == 63) ? 0ULL : (bm[wi] & (~0ULL << (bi + 1)));
    while (m == 0ULL && wi < NWORD - 1) m = bm[++wi];
    return m ? ((wi << 6) + (__ffsll((unsigned long long)m) - 1)) : -1;
}

__global__ __launch_bounds__(NTH) void blur_phoneme_kernel(
    const int* __restrict__ ids, const float* __restrict__ table,
    float* __restrict__ out, int T, int D)
{
    __shared__ int sid[SSTAGE];
    __shared__ unsigned long long bmask[NWORD];
    __shared__ float s_w[TILE];
    __shared__ int s_nb[TILE];

    const int b   = blockIdx.y;
    const int t0  = blockIdx.x * TILE;
    const int tid = threadIdx.x;
    const int* __restrict__ row = ids + (size_t)b * T;

    // ---- stage ids (clamped range reads 0; never consumed out-of-range) ----
    for (int i = tid; i < SSTAGE; i += NTH) {
        int t = t0 - HALO + i;
        sid[i] = (t >= 0 && t < T) ? row[t] : 0;
    }
    __syncthreads();

    // ---- boundary bitmask via wave ballot: bit set iff is_start(t) ----
    // is_start(0)=1; is_start(t in (0,T)) = ids[t]!=ids[t-1]; is_start(t>=T)=1 (virtual end).
    for (int i = tid; i < SSTAGE; i += NTH) {
        int t = t0 - HALO + i;
        bool pred;
        if (t <= 0)      pred = (t == 0);
        else if (t >= T) pred = true;
        else {
            int prv = (i >= 1) ? sid[i - 1] : row[t - 1];
            pred = (sid[i] != prv);
        }
        unsigned long long m = __ballot(pred);
        if ((tid & 63) == 0) bmask[i >> 6] = m;  // wave-contiguous: word = i/64
    }
    __syncthreads();

    // ---- per-position weight + neighbor (one thread per tile position) ----
    {
        const int li = HALO + tid;
        const int t  = t0 + tid;
        int s_loc = bits_le(bmask, li);
        int e_loc = bits_gt(bmask, li);
        int start = (s_loc >= 0) ? (t0 - HALO + s_loc) : seg_start_global(row, t);
        int end   = (e_loc >= 0) ? (t0 - HALO + e_loc) : seg_end_global(row, t, T);
        int dur   = end - start;
        int myid  = sid[li];

        float w_n = 0.f, w_p = 0.f;
        int nid = myid, pid = myid;

        // right boundary (ramp toward next phoneme)
        if (end < T) {
            int nxt_id, nend;
            if (e_loc >= 0) {
                nxt_id = sid[e_loc];
                int n_loc = bits_gt(bmask, e_loc);
                nend = (n_loc >= 0) ? (t0 - HALO + n_loc) : seg_end_global(row, end, T);
            } else {
                nxt_id = row[end];
                nend = seg_end_global(row, end, T);
            }
            float rad_n = BFC * (float)min(dur, nend - end);       // f32, matches jnp
            if (rad_n >= 0.5f) {
                int rn = max(1, (int)rintf(rad_n));                 // round half-to-even
                int left_start = max(0, end - rn);
                if (t >= left_start) {
                    w_n = fminf(0.5f * (float)(t - left_start + 1) / (float)rn, 0.5f);
                    nid = nxt_id;
                }
            }
        }
        // left boundary (ramp from previous phoneme)
        if (start > 0) {
            int prv_id, pstart;
            if (s_loc >= 1) {
                prv_id = sid[s_loc - 1];
                int p_loc = bits_le(bmask, s_loc - 1);
                pstart = (p_loc >= 0) ? (t0 - HALO + p_loc) : seg_start_global(row, start - 1);
            } else {
                prv_id = row[start - 1];
                pstart = seg_start_global(row, start - 1);
            }
            float rad_p = BFC * (float)min(start - pstart, dur);
            if (rad_p >= 0.5f) {
                int rp = max(1, (int)rintf(rad_p));
                int right_end = min(T, start + rp);
                if (t < right_end) {
                    w_p = fminf(0.5f * (float)(right_end - t) / (float)rp, 0.5f);
                    pid = prv_id;
                }
            }
        }
        s_w[tid]  = fmaxf(w_p, w_n);
        // ties (w_n == w_p) keep prev-boundary id, exactly like the reference
        s_nb[tid] = (w_n > w_p) ? nid : ((w_p > 0.f) ? pid : myid);
    }
    __syncthreads();

    // ---- gather + blend + coalesced float4 store ----
    const int DC = D >> 2;                                   // 16 float4 per row
    const float4* __restrict__ tbl4 = reinterpret_cast<const float4*>(table);
    float4* __restrict__ out4 = reinterpret_cast<float4*>(out);
    size_t base = ((size_t)b * T + t0) * DC;
    for (int idx = tid; idx < TILE * DC; idx += NTH) {
        int p = idx / DC;
        int c = idx - p * DC;
        int id = sid[HALO + p];
        int nb = s_nb[p];
        float w = s_w[p];
        float4 ea = (id != 0) ? tbl4[(size_t)id * DC + c] : float4{0.f, 0.f, 0.f, 0.f};
        float4 eb = (nb == id) ? ea
                  : ((nb != 0) ? tbl4[(size_t)nb * DC + c] : float4{0.f, 0.f, 0.f, 0.f});
        float a = 1.0f - w;
        float4 o;
        o.x = a * ea.x + w * eb.x;
        o.y = a * ea.y + w * eb.y;
        o.z = a * ea.z + w * eb.z;
        o.w = a * ea.w + w * eb.w;
        out4[base + idx] = o;
    }
}

extern "C" void kernel_launch(void* const* d_in, const int* in_sizes, int n_in,
                              void* d_out, int out_size, void* d_ws, size_t ws_size,
                              hipStream_t stream) {
    const int*   ids   = (const int*)d_in[0];    // (B,T) int32 (JAX x64 off)
    const float* table = (const float*)d_in[1];  // (V,D) f32
    float*       out   = (float*)d_out;          // (B,T,D) f32

    const int n_ids = in_sizes[0];               // B*T
    const int D = out_size / n_ids;              // 64
    const int T = 8192;                          // fixed by setup_inputs
    const int B = n_ids / T;                     // 32

    dim3 grid(T / TILE, B);                      // (32, 32) = 1024 blocks
    blur_phoneme_kernel<<<grid, NTH, 0, stream>>>(ids, table, out, T, D);
}

// Round 2
// 82.552 us; speedup vs baseline: 1.0564x; 1.0564x over previous
//
#include <hip/hip_runtime.h>

// BlurredPhonemeEmbedding on MI355X (gfx950).
// B=32, T=8192, V=2820, D=64. Output (B,T,D) f32 = 64 MiB -> write-bound.
// Fused kernel: per 256-position tile, stage ids (+256 halo) in LDS, build
// segment-boundary bitmask via __ballot, derive blend weight + neighbor id
// with word bit-scans, then fully-unrolled float4 gather-blend with
// nontemporal stores (keep the 722 KB table resident in L2).

#define BFC    0.3f
#define TLEN   8192
#define TILE   256
#define HALO   256
#define SSTAGE (TILE + 2 * HALO)   // 768 staged positions
#define NWORD  (SSTAGE / 64)       // 12 bitmask words
#define NTH    256
#define DC     16                  // D/4 = 16 float4 per embedding row

typedef float f4 __attribute__((ext_vector_type(4)));

// Rare fallback paths (halo exhausted): scan global ids directly (L2-hot).
__device__ __forceinline__ int seg_start_global(const int* __restrict__ row, int t) {
    while (t > 0 && row[t] == row[t - 1]) --t;   // stop at is_start
    return t;
}
__device__ __forceinline__ int seg_end_global(const int* __restrict__ row, int t) {
    ++t;
    while (t < TLEN && row[t] == row[t - 1]) ++t; // smallest boundary > t
    return t;
}

// largest set bit index <= li, or -1
__device__ __forceinline__ int bits_le(const unsigned long long* bm, int li) {
    int wi = li >> 6, bi = li & 63;
    unsigned long long m = bm[wi] & (~0ULL >> (63 - bi));
    while (m == 0ULL && wi > 0) m = bm[--wi];
    return m ? ((wi << 6) + 63 - __clzll((long long)m)) : -1;
}
// smallest set bit index > li, or -1
__device__ __forceinline__ int bits_gt(const unsigned long long* bm, int li) {
    int wi = li >> 6, bi = li & 63;
    unsigned long long m = (bi == 63) ? 0ULL : (bm[wi] & (~0ULL << (bi + 1)));
    while (m == 0ULL && wi < NWORD - 1) m = bm[++wi];
    return m ? ((wi << 6) + (__ffsll(m) - 1)) : -1;
}

__global__ __launch_bounds__(NTH) void blur_phoneme_kernel(
    const int* __restrict__ ids, const float* __restrict__ table,
    float* __restrict__ out)
{
    __shared__ int sid[SSTAGE];
    __shared__ unsigned long long bmask[NWORD];
    __shared__ float2 s_wn[TILE];    // .x = blend weight, .y = neighbor id (bits)

    const int b   = blockIdx.y;
    const int t0  = blockIdx.x * TILE;
    const int tid = threadIdx.x;
    const int* __restrict__ row = ids + (size_t)b * TLEN;

    // ---- stage ids (out-of-range reads 0; never consumed out-of-range) ----
    #pragma unroll
    for (int k = 0; k < SSTAGE / NTH; ++k) {
        int i = tid + k * NTH;
        int t = t0 - HALO + i;
        sid[i] = (t >= 0 && t < TLEN) ? row[t] : 0;
    }
    __syncthreads();

    // ---- boundary bitmask via wave ballot: bit set iff is_start(t) ----
    // is_start(0)=1; is_start(t in (0,T)) = ids[t]!=ids[t-1]; t>=T virtual end.
    #pragma unroll
    for (int k = 0; k < SSTAGE / NTH; ++k) {
        int i = tid + k * NTH;
        int t = t0 - HALO + i;
        bool pred;
        if (t <= 0)         pred = (t == 0);
        else if (t >= TLEN) pred = true;
        else {
            int prv = (i >= 1) ? sid[i - 1] : row[t - 1];
            pred = (sid[i] != prv);
        }
        unsigned long long m = __ballot(pred);
        if ((tid & 63) == 0) bmask[i >> 6] = m;   // wave-contiguous words
    }
    __syncthreads();

    // ---- per-position weight + neighbor (one thread per tile position) ----
    {
        const int li = HALO + tid;
        const int t  = t0 + tid;
        int s_loc = bits_le(bmask, li);
        int e_loc = bits_gt(bmask, li);
        int start = (s_loc >= 0) ? (t0 - HALO + s_loc) : seg_start_global(row, t);
        int end   = (e_loc >= 0) ? (t0 - HALO + e_loc) : seg_end_global(row, t);
        int dur   = end - start;
        int myid  = sid[li];

        float w_n = 0.f, w_p = 0.f;
        int nid = myid, pid = myid;

        // right boundary (ramp toward next phoneme)
        if (end < TLEN) {
            int nxt_id, nend;
            if (e_loc >= 0) {
                nxt_id = sid[e_loc];
                int n_loc = bits_gt(bmask, e_loc);
                nend = (n_loc >= 0) ? (t0 - HALO + n_loc) : seg_end_global(row, end);
            } else {
                nxt_id = row[end];
                nend = seg_end_global(row, end);
            }
            float rad_n = BFC * (float)min(dur, nend - end);     // f32, matches jnp
            if (rad_n >= 0.5f) {
                int rn = max(1, (int)rintf(rad_n));              // round half-to-even
                int left_start = max(0, end - rn);
                if (t >= left_start) {
                    w_n = fminf(0.5f * (float)(t - left_start + 1) / (float)rn, 0.5f);
                    nid = nxt_id;
                }
            }
        }
        // left boundary (ramp from previous phoneme)
        if (start > 0) {
            int prv_id, pstart;
            if (s_loc >= 1) {
                prv_id = sid[s_loc - 1];
                int p_loc = bits_le(bmask, s_loc - 1);
                pstart = (p_loc >= 0) ? (t0 - HALO + p_loc) : seg_start_global(row, start - 1);
            } else {
                prv_id = row[start - 1];
                pstart = seg_start_global(row, start - 1);
            }
            float rad_p = BFC * (float)min(start - pstart, dur);
            if (rad_p >= 0.5f) {
                int rp = max(1, (int)rintf(rad_p));
                int right_end = min(TLEN, start + rp);
                if (t < right_end) {
                    w_p = fminf(0.5f * (float)(right_end - t) / (float)rp, 0.5f);
                    pid = prv_id;
                }
            }
        }
        float w = fmaxf(w_p, w_n);
        // ties (w_n == w_p) keep prev-boundary id, exactly like the reference
        int nb = (w_n > w_p) ? nid : ((w_p > 0.f) ? pid : myid);
        s_wn[tid] = make_float2(w, __int_as_float(nb));
    }
    __syncthreads();

    // ---- gather + blend + coalesced nontemporal float4 store ----
    // thread -> fixed chunk c = tid&15; positions p = (tid>>4) + 16k, k=0..15.
    const f4* __restrict__ tbl4 = reinterpret_cast<const f4*>(table);
    f4* __restrict__ out4 = reinterpret_cast<f4*>(out) + ((size_t)b * TLEN + t0) * DC;
    const int c  = tid & (DC - 1);
    const int p0 = tid >> 4;
    #pragma unroll
    for (int k = 0; k < TILE * DC / NTH; ++k) {
        int p = p0 + (k << 4);
        int id = sid[HALO + p];
        float2 wn = s_wn[p];
        int nb = __float_as_int(wn.y);
        float w = wn.x;
        // always issue both gathers (uniform control flow, 2x MLP; L2-hot)
        f4 ea = tbl4[id * DC + c];
        f4 eb = tbl4[nb * DC + c];
        float wa = (id != 0) ? (1.0f - w) : 0.0f;   // padding_idx guard
        float wb = (nb != 0) ? w : 0.0f;
        f4 o = ea * wa + eb * wb;
        __builtin_nontemporal_store(o, &out4[tid + (k << 8)]);
    }
}

extern "C" void kernel_launch(void* const* d_in, const int* in_sizes, int n_in,
                              void* d_out, int out_size, void* d_ws, size_t ws_size,
                              hipStream_t stream) {
    const int*   ids   = (const int*)d_in[0];    // (B,T) int32
    const float* table = (const float*)d_in[1];  // (V,D) f32
    float*       out   = (float*)d_out;          // (B,T,D) f32

    const int n_ids = in_sizes[0];               // B*T
    const int B = n_ids / TLEN;                  // 32

    dim3 grid(TLEN / TILE, B);                   // (32, 32) = 1024 blocks
    blur_phoneme_kernel<<<grid, NTH, 0, stream>>>(ids, table, out);
}